// Round 2
// baseline (354.456 us; speedup 1.0000x reference)
//
#include <hip/hip_runtime.h>
#include <stdint.h>

// int8-quantized GEMM: out[m,n] = (sum_k x[m,k]*w[n,k]) * x_scale * w_scale, fp32 out.
// M=64, K=4096, N=14336.
// Harness materializes integer inputs as int32 -> weights are 235 MB: HBM-bound,
// floor ~38 us at 6.3 TB/s. Strategy: stream int32 weights, v_perm-pack to int8
// in-register, i8 MFMA. x is packed to int8 once into d_ws by a pre-kernel so the
// per-block x re-read (896 blocks x full x) stays at 224 MB of L2/L3 traffic.
#define MDIM 64
#define KDIM 4096
#define NDIM 14336

typedef int v4i __attribute__((ext_vector_type(4)));

// pack4: low bytes of 4 sign-extended int32s -> one int (4 int8s).
// v_perm_b32 combined bytes: [0..3]=src1, [4..7]=src0 (builtin arg order (src0,src1,sel)).
__device__ __forceinline__ int pack4(int w0, int w1, int w2, int w3) {
    int t01 = __builtin_amdgcn_perm(w1, w0, 0x00000400u);  // b0=w0.b0, b1=w1.b0
    int t23 = __builtin_amdgcn_perm(w3, w2, 0x00000400u);  // b0=w2.b0, b1=w3.b0
    return  __builtin_amdgcn_perm(t23, t01, 0x05040100u);  // (w0,w1,w2,w3) low bytes
}

// Pre-kernel: pack x [64,4096] int32 -> int8 into d_ws (256 KB).
__global__ void pack_x_kernel(const int* __restrict__ xi, int* __restrict__ xo) {
    const int i = blockIdx.x * 256 + threadIdx.x;      // packed-word index, 65536 total
    const int* p = xi + (size_t)i * 4;
    v4i w = *(const v4i*)p;
    xo[i] = pack4(w[0], w[1], w[2], w[3]);
}

// One block = 4 waves, one 16-wide N tile. Each wave: 4 M-tiles over K/4=1024.
// mfma_i32_16x16x64_i8: lane holds 16 contiguous K int8s (k=(lane>>4)*16+j),
// row/col = lane&15. Split-K reduced through LDS in the epilogue.
__global__ __launch_bounds__(256, 2) void gemm_i8_kernel(
    const int8_t* __restrict__ xp8,   // packed x (d_ws)
    const float*  __restrict__ xs,
    const int*    __restrict__ wq32,  // int32 weights
    const float*  __restrict__ wscale,
    float*        __restrict__ out)
{
    const int tid  = threadIdx.x;
    const int wave = tid >> 6;
    const int lane = tid & 63;
    const int r    = lane & 15;   // m within A tile / n within B tile
    const int kg   = lane >> 4;   // k-group 0..3
    const int n0   = blockIdx.x * 16;

    const int kbase = wave * (KDIM / 4) + kg * 16;   // element index along K

    const int*    wp = wq32 + (size_t)(n0 + r) * KDIM + kbase;
    const int8_t* xp = xp8  + (size_t)r * KDIM + kbase;

    v4i acc0 = {0, 0, 0, 0};
    v4i acc1 = {0, 0, 0, 0};
    v4i acc2 = {0, 0, 0, 0};
    v4i acc3 = {0, 0, 0, 0};

    #pragma unroll
    for (int ks = 0; ks < 16; ++ks) {
        const int koff = ks * 64;   // K elements per step per wave-slice
        // Weights: 16 int32 -> 16 int8 (64 B load -> 16 B fragment)
        v4i w0 = *(const v4i*)(wp + koff);
        v4i w1 = *(const v4i*)(wp + koff + 4);
        v4i w2 = *(const v4i*)(wp + koff + 8);
        v4i w3 = *(const v4i*)(wp + koff + 12);
        v4i b;
        b[0] = pack4(w0[0], w0[1], w0[2], w0[3]);
        b[1] = pack4(w1[0], w1[1], w1[2], w1[3]);
        b[2] = pack4(w2[0], w2[1], w2[2], w2[3]);
        b[3] = pack4(w3[0], w3[1], w3[2], w3[3]);

        v4i a0 = *(const v4i*)(xp + koff);
        v4i a1 = *(const v4i*)(xp + 16 * KDIM + koff);
        v4i a2 = *(const v4i*)(xp + 32 * KDIM + koff);
        v4i a3 = *(const v4i*)(xp + 48 * KDIM + koff);

        acc0 = __builtin_amdgcn_mfma_i32_16x16x64_i8(a0, b, acc0, 0, 0, 0);
        acc1 = __builtin_amdgcn_mfma_i32_16x16x64_i8(a1, b, acc1, 0, 0, 0);
        acc2 = __builtin_amdgcn_mfma_i32_16x16x64_i8(a2, b, acc2, 0, 0, 0);
        acc3 = __builtin_amdgcn_mfma_i32_16x16x64_i8(a3, b, acc3, 0, 0, 0);
    }

    // Split-K reduction: red[src_wave][m_tile][lane*4 + i]
    __shared__ int red[4][4][256];
    ((v4i*)red[wave][0])[lane] = acc0;
    ((v4i*)red[wave][1])[lane] = acc1;
    ((v4i*)red[wave][2])[lane] = acc2;
    ((v4i*)red[wave][3])[lane] = acc3;
    __syncthreads();

    // Wave w reduces m-tile w across the 4 K-slices.
    v4i s0 = ((v4i*)red[0][wave])[lane];
    v4i s1 = ((v4i*)red[1][wave])[lane];
    v4i s2 = ((v4i*)red[2][wave])[lane];
    v4i s3 = ((v4i*)red[3][wave])[lane];
    v4i tot = s0 + s1 + s2 + s3;

    const float scale = xs[0] * wscale[0];
    // C/D layout: col = lane&15, row = (lane>>4)*4 + reg  [measured m89/m127]
    const int mbase = wave * 16 + kg * 4;
    const int n = n0 + r;
    #pragma unroll
    for (int i = 0; i < 4; ++i) {
        out[(size_t)(mbase + i) * NDIM + n] = scale * (float)tot[i];
    }
}

extern "C" void kernel_launch(void* const* d_in, const int* in_sizes, int n_in,
                              void* d_out, int out_size, void* d_ws, size_t ws_size,
                              hipStream_t stream) {
    const int*   xq32   = (const int*)d_in[0];    // int8 values materialized as int32
    const float* xs     = (const float*)d_in[1];
    const int*   wq32   = (const int*)d_in[2];
    const float* wscale = (const float*)d_in[3];
    float* out = (float*)d_out;

    int* x_packed = (int*)d_ws;                    // 256 KB of d_ws

    // Pack x: 64*4096 = 262144 values -> 65536 packed words.
    pack_x_kernel<<<256, 256, 0, stream>>>(xq32, x_packed);

    const int nblocks = NDIM / 16;  // 896
    gemm_i8_kernel<<<nblocks, 256, 0, stream>>>((const int8_t*)x_packed, xs, wq32, wscale, out);
}

// Round 4
// 351.957 us; speedup vs baseline: 1.0071x; 1.0071x over previous
//
#include <hip/hip_runtime.h>
#include <stdint.h>

// int8-quantized GEMM: out[m,n] = (sum_k x[m,k]*w[n,k]) * x_scale * w_scale, fp32 out.
// M=64, K=4096, N=14336. Inputs materialized as int32 -> weights are 235 MB.
// HBM-bound: floor ~38 us at 6.3 TB/s.
// R2 lesson: register-streaming caps in-flight bytes (VGPR-limited) -> 0.66 TB/s.
// R3 lesson: compiler does NOT order global_load_lds -> ds_read without a barrier;
//            explicit `s_waitcnt vmcnt(0)` is required in a barrier-free K-loop.
#define KDIM 4096
#define NDIM 14336
#define STEPS 16  // 1024-elem wave K-slice / 64 per step

typedef int v4i __attribute__((ext_vector_type(4)));

// pack4: low bytes of 4 sign-extended int32s -> one int (4 int8s).
__device__ __forceinline__ int pack4(int w0, int w1, int w2, int w3) {
    int t01 = __builtin_amdgcn_perm(w1, w0, 0x00000400u);  // b0=w0.b0, b1=w1.b0
    int t23 = __builtin_amdgcn_perm(w3, w2, 0x00000400u);
    return  __builtin_amdgcn_perm(t23, t01, 0x05040100u);  // low bytes of (w0..w3)
}

// Pre-kernel: pack x [64,4096] int32 -> int8 into d_ws (256 KB).
__global__ void pack_x_kernel(const int* __restrict__ xi, int* __restrict__ xo) {
    const int i = blockIdx.x * 256 + threadIdx.x;  // 65536 packed words
    v4i w = *(const v4i*)(xi + (size_t)i * 4);
    xo[i] = pack4(w[0], w[1], w[2], w[3]);
}

// Async 16B/lane global->LDS. LDS dest semantics: wave-uniform base + lane*16.
#define GLD_LDS(gptr, lptr) \
    __builtin_amdgcn_global_load_lds( \
        (const __attribute__((address_space(1))) int*)(const void*)(gptr), \
        (__attribute__((address_space(3))) int*)(void*)(lptr), 16, 0, 0)

// One block = 4 waves, one 16-wide N tile, split-K 4 ways across waves.
// mfma_i32_16x16x64_i8 fragments: row/col = lane&15, k = (lane>>4)*16 + j,
// 16 contiguous K int8s per lane (validated end-to-end in round 2).
__global__ __launch_bounds__(256, 4) void gemm_i8_kernel(
    const int8_t* __restrict__ xp8,   // packed x (d_ws)
    const float*  __restrict__ xs,
    const int*    __restrict__ wq32,  // int32 weights
    const float*  __restrict__ wscale,
    float*        __restrict__ out)
{
    // [buf][wave][issue][256 ints] = 32 KB. Each wave stages/consumes only its
    // own region -> no K-loop barrier; explicit vmcnt(0) orders DMA -> ds_read.
    __shared__ int lds[2][4][4][256];

    const int tid  = threadIdx.x;
    const int wave = tid >> 6;
    const int lane = tid & 63;
    const int r    = lane & 15;   // m within A tile / n within B tile
    const int kg   = lane >> 4;   // k-group 0..3
    const int n0   = blockIdx.x * 16;

    const int kbase = wave * 1024 + kg * 16;  // element index along K

    const int*    wp = wq32 + (size_t)(n0 + r) * KDIM + kbase;
    const int8_t* xp = xp8  + (size_t)r * KDIM + kbase;

    // Prologue: stage step-0 weights (4 x 16B/lane = 16 int32/lane) into buf 0.
    #pragma unroll
    for (int j = 0; j < 4; ++j)
        GLD_LDS(wp + j * 4, &lds[0][wave][j][0]);

    // Step-0 x fragments (L2-hot).
    v4i a[4];
    #pragma unroll
    for (int t = 0; t < 4; ++t)
        a[t] = *(const v4i*)(xp + t * 16 * KDIM);

    v4i acc[4];
    #pragma unroll
    for (int t = 0; t < 4; ++t) acc[t] = (v4i){0, 0, 0, 0};

    int buf = 0;
    for (int ks = 0; ks < STEPS; ++ks) {
        // Drain the staging DMA for `buf` (issued one iter ago) AND last iter's
        // x prefetch. REQUIRED: compiler emits no wait between global_load_lds
        // and ds_read on its own (R3 failure).
        asm volatile("s_waitcnt vmcnt(0)" ::: "memory");

        v4i wreg[4];
        #pragma unroll
        for (int j = 0; j < 4; ++j)
            wreg[j] = *(const v4i*)&lds[buf][wave][j][lane * 4];

        // Stage next step into the other buffer; stays in flight across compute.
        if (ks + 1 < STEPS) {
            const int* wnext = wp + (ks + 1) * 64;
            #pragma unroll
            for (int j = 0; j < 4; ++j)
                GLD_LDS(wnext + j * 4, &lds[buf ^ 1][wave][j][0]);
            // Prefetch next step's x fragments (drained by next iter's vmcnt(0)).
            #pragma unroll
            for (int t = 0; t < 4; ++t)
                a[t + 4 - 4] = a[t];  // keep current a live (no-op; clarity)
        }

        v4i anext[4];
        if (ks + 1 < STEPS) {
            const int kn = (ks + 1) * 64;
            #pragma unroll
            for (int t = 0; t < 4; ++t)
                anext[t] = *(const v4i*)(xp + t * 16 * KDIM + kn);
        }

        // Pack 16 int32 -> 16 int8 B-fragment (lgkm wait auto-inserted for wreg).
        v4i b;
        b[0] = pack4(wreg[0][0], wreg[0][1], wreg[0][2], wreg[0][3]);
        b[1] = pack4(wreg[1][0], wreg[1][1], wreg[1][2], wreg[1][3]);
        b[2] = pack4(wreg[2][0], wreg[2][1], wreg[2][2], wreg[2][3]);
        b[3] = pack4(wreg[3][0], wreg[3][1], wreg[3][2], wreg[3][3]);

        acc[0] = __builtin_amdgcn_mfma_i32_16x16x64_i8(a[0], b, acc[0], 0, 0, 0);
        acc[1] = __builtin_amdgcn_mfma_i32_16x16x64_i8(a[1], b, acc[1], 0, 0, 0);
        acc[2] = __builtin_amdgcn_mfma_i32_16x16x64_i8(a[2], b, acc[2], 0, 0, 0);
        acc[3] = __builtin_amdgcn_mfma_i32_16x16x64_i8(a[3], b, acc[3], 0, 0, 0);

        if (ks + 1 < STEPS) {
            #pragma unroll
            for (int t = 0; t < 4; ++t) a[t] = anext[t];
        }
        buf ^= 1;
    }

    // Split-K reduction. Reuse lds[0] (all DMA drained by the last vmcnt(0);
    // no staging issued on the final iter). red[src_wave][m_tile][256].
    int (*red)[4][256] = (int (*)[4][256]) & lds[0][0][0][0];
    ((v4i*)red[wave][0])[lane] = acc[0];
    ((v4i*)red[wave][1])[lane] = acc[1];
    ((v4i*)red[wave][2])[lane] = acc[2];
    ((v4i*)red[wave][3])[lane] = acc[3];
    __syncthreads();

    v4i s0 = ((v4i*)red[0][wave])[lane];
    v4i s1 = ((v4i*)red[1][wave])[lane];
    v4i s2 = ((v4i*)red[2][wave])[lane];
    v4i s3 = ((v4i*)red[3][wave])[lane];
    v4i tot = s0 + s1 + s2 + s3;

    const float scale = xs[0] * wscale[0];
    // C/D layout: col = lane&15, row = (lane>>4)*4 + reg  [validated round 2]
    const int mbase = wave * 16 + kg * 4;
    const int n = n0 + r;
    #pragma unroll
    for (int i = 0; i < 4; ++i)
        out[(size_t)(mbase + i) * NDIM + n] = scale * (float)tot[i];
}

extern "C" void kernel_launch(void* const* d_in, const int* in_sizes, int n_in,
                              void* d_out, int out_size, void* d_ws, size_t ws_size,
                              hipStream_t stream) {
    const int*   xq32   = (const int*)d_in[0];
    const float* xs     = (const float*)d_in[1];
    const int*   wq32   = (const int*)d_in[2];
    const float* wscale = (const float*)d_in[3];
    float* out = (float*)d_out;

    int* x_packed = (int*)d_ws;  // 256 KB of d_ws

    pack_x_kernel<<<256, 256, 0, stream>>>(xq32, x_packed);

    const int nblocks = NDIM / 16;  // 896
    gemm_i8_kernel<<<nblocks, 256, 0, stream>>>((const int8_t*)x_packed, xs, wq32, wscale, out);
}

// Round 5
// 322.178 us; speedup vs baseline: 1.1002x; 1.0924x over previous
//
#include <hip/hip_runtime.h>
#include <stdint.h>

// int8-quantized GEMM: out[m,n] = (sum_k x[m,k]*w[n,k]) * x_scale * w_scale, fp32 out.
// M=64, K=4096, N=14336. Inputs materialized as int32 -> weights are 235 MB.
// HBM-bound: floor ~38 us at 6.3 TB/s.
// R2/R4 lesson: fragment-shaped weight loads (64 distinct 64B sectors per
// instruction) cap effective BW at ~1.9 TB/s regardless of sync-vs-async.
// This version: m97-style block staging -- every global_load_lds covers 1 KB
// FULLY CONTIGUOUS (one weight row segment), double-buffered + barriered.
// M split across waves (no split-K), fragments read from LDS with a
// bank-uniform 1040 B row pitch.
#define KDIM 4096
#define NDIM 14336
#define KSTEP 256                 // int32 elements per row per step (1 KB)
#define NSTEPS (KDIM / KSTEP)     // 16
#define ROWW 260                  // LDS row pitch in ints; 260 % 32 == 4 -> uniform banks

typedef int v4i __attribute__((ext_vector_type(4)));

// pack4: low bytes of 4 sign-extended int32s -> one int (4 int8s).
__device__ __forceinline__ int pack4(int w0, int w1, int w2, int w3) {
    int t01 = __builtin_amdgcn_perm(w1, w0, 0x00000400u);  // b0=w0.b0, b1=w1.b0
    int t23 = __builtin_amdgcn_perm(w3, w2, 0x00000400u);
    return  __builtin_amdgcn_perm(t23, t01, 0x05040100u);  // low bytes of (w0..w3)
}

// Pre-kernel: pack x [64,4096] int32 -> int8 into d_ws (256 KB).
__global__ void pack_x_kernel(const int* __restrict__ xi, int* __restrict__ xo) {
    const int i = blockIdx.x * 256 + threadIdx.x;  // 65536 packed words
    v4i w = *(const v4i*)(xi + (size_t)i * 4);
    xo[i] = pack4(w[0], w[1], w[2], w[3]);
}

// Async 16B/lane global->LDS; lands at lds_base + lane*16 (wave-uniform base).
#define GLD_LDS(gptr, lptr) \
    __builtin_amdgcn_global_load_lds( \
        (const __attribute__((address_space(1))) int*)(const void*)(gptr), \
        (__attribute__((address_space(3))) int*)(void*)(lptr), 16, 0, 0)

// Block = 4 waves, 16-wide N tile. Wave w computes m-tile w (16 rows of x)
// against the shared 16-row weight tile staged in LDS.
// mfma_i32_16x16x64_i8 fragments (validated R2): row/col = lane&15,
// k = (lane>>4)*16 + j, 16 contiguous K int8s per lane.
__global__ __launch_bounds__(256, 4) void gemm_i8_kernel(
    const int8_t* __restrict__ xp8,   // packed x (d_ws)
    const float*  __restrict__ xs,
    const int*    __restrict__ wq32,  // int32 weights
    const float*  __restrict__ wscale,
    float*        __restrict__ out)
{
    // Double-buffered staged weight tile: [buf][row 0..15][KSTEP ints + pad].
    // 2*16*1040 B = 32.5 KB -> 4 blocks/CU.
    __shared__ int lds[2][16][ROWW];

    const int tid  = threadIdx.x;
    const int wave = tid >> 6;
    const int lane = tid & 63;
    const int r    = lane & 15;   // n within tile (B) / m within m-tile (A)
    const int kg   = lane >> 4;   // k-group 0..3
    const int n0   = blockIdx.x * 16;

    // Per-lane staging source: wave stages rows wave*4+j, lane covers ints [lane*4, +4).
    const int* wsrc[4];
    #pragma unroll
    for (int j = 0; j < 4; ++j)
        wsrc[j] = wq32 + (size_t)(n0 + wave * 4 + j) * KDIM + lane * 4;

    // x: wave's m-tile row (wave*16 + r), fragment base at kg*16.
    const int8_t* xp = xp8 + (size_t)(wave * 16 + r) * KDIM + kg * 16;

    // Prologue: stage step 0 into buf 0 (fully contiguous 1 KB per instruction).
    #pragma unroll
    for (int j = 0; j < 4; ++j)
        GLD_LDS(wsrc[j], &lds[0][wave * 4 + j][0]);

    // Prologue: step-0 A fragments (L2-hot packed x).
    v4i ax[4];
    #pragma unroll
    for (int kc = 0; kc < 4; ++kc)
        ax[kc] = *(const v4i*)(xp + kc * 64);

    v4i acc = {0, 0, 0, 0};

    for (int ks = 0; ks < NSTEPS; ++ks) {
        const int buf = ks & 1;

        // Drain staging DMA (+ x prefetch) before anyone reads the buffer.
        // Compiler also drains before s_barrier; explicit for safety (R3 lesson).
        asm volatile("s_waitcnt vmcnt(0)" ::: "memory");
        __syncthreads();

        // Stage next step into the other buffer (its old contents were consumed
        // before the barrier we just crossed -> WAR-safe). Stays in flight
        // across this step's compute on all 4 co-resident blocks.
        if (ks + 1 < NSTEPS) {
            #pragma unroll
            for (int j = 0; j < 4; ++j)
                GLD_LDS(wsrc[j] + (ks + 1) * KSTEP, &lds[buf ^ 1][wave * 4 + j][0]);
        }

        // Prefetch next step's A fragments (drained by next iter's vmcnt(0)).
        v4i axn[4];
        if (ks + 1 < NSTEPS) {
            #pragma unroll
            for (int kc = 0; kc < 4; ++kc)
                axn[kc] = *(const v4i*)(xp + (ks + 1) * KSTEP + kc * 64);
        }

        // Consume staged tile: per k-chunk (K=64), read B-fragment (16 int32),
        // pack to 16 int8, MFMA.
        const char* lrow = (const char*)&lds[buf][r][0];
        #pragma unroll
        for (int kc = 0; kc < 4; ++kc) {
            const char* p = lrow + kc * 256 + kg * 64;
            v4i w0 = *(const v4i*)(p);
            v4i w1 = *(const v4i*)(p + 16);
            v4i w2 = *(const v4i*)(p + 32);
            v4i w3 = *(const v4i*)(p + 48);
            v4i b;
            b[0] = pack4(w0[0], w0[1], w0[2], w0[3]);
            b[1] = pack4(w1[0], w1[1], w1[2], w1[3]);
            b[2] = pack4(w2[0], w2[1], w2[2], w2[3]);
            b[3] = pack4(w3[0], w3[1], w3[2], w3[3]);
            acc = __builtin_amdgcn_mfma_i32_16x16x64_i8(ax[kc], b, acc, 0, 0, 0);
        }

        if (ks + 1 < NSTEPS) {
            #pragma unroll
            for (int kc = 0; kc < 4; ++kc) ax[kc] = axn[kc];
        }
    }

    // Epilogue: wave w owns its 16x16 tile; no cross-wave reduction.
    // C/D layout: col = lane&15, row = (lane>>4)*4 + reg  [validated R2].
    const float scale = xs[0] * wscale[0];
    const int n = n0 + r;
    const int mbase = wave * 16 + kg * 4;
    #pragma unroll
    for (int i = 0; i < 4; ++i)
        out[(size_t)(mbase + i) * NDIM + n] = scale * (float)acc[i];
}

extern "C" void kernel_launch(void* const* d_in, const int* in_sizes, int n_in,
                              void* d_out, int out_size, void* d_ws, size_t ws_size,
                              hipStream_t stream) {
    const int*   xq32   = (const int*)d_in[0];
    const float* xs     = (const float*)d_in[1];
    const int*   wq32   = (const int*)d_in[2];
    const float* wscale = (const float*)d_in[3];
    float* out = (float*)d_out;

    int* x_packed = (int*)d_ws;  // 256 KB of d_ws

    pack_x_kernel<<<256, 256, 0, stream>>>(xq32, x_packed);

    const int nblocks = NDIM / 16;  // 896
    gemm_i8_kernel<<<nblocks, 256, 0, stream>>>((const int8_t*)x_packed, xs, wq32, wscale, out);
}